// Round 14
// baseline (166.411 us; speedup 1.0000x reference)
//
#include <hip/hip_runtime.h>
#include <math.h>

#define HEADS 8
#define DIM   64
#define DK    24
#define DHK   3
#define BB    4
#define HH    128
#define WW    128
#define NN    (HH*WW)
#define QSCALE 0.125f

// ---------------------------------------------------------------------------
// K1': token-partial reduce + IN-BLOCK linear projection to att-space.
// Everything before softmax is linear, so per-block partials can be
// projected (S_blk = Wk^T Sp_blk; att_blk = S_blk Wq * QSCALE * rescale)
// and summed later -- this is what lets slab_reduce+attn collapse into one
// row-parallel kernel (dispatch overhead ~19us each; R11->R12 fit).
// grid 1024 x 256. v6-proven staging + merge; then E: S_l; F: per-h Wq
// staged to LDS (16KB, coalesced), att outputs stored to att_part.
// LDS 30.8KB -> 5 blocks/CU.
// ---------------------------------------------------------------------------
__global__ __launch_bounds__(256) void s_reduce_proj(
    const float* __restrict__ imap,    // [B*N,24]
    const float* __restrict__ x,       // [B*N,64]
    const float* __restrict__ Wk,      // [24,24]
    const float* __restrict__ Wq,      // [64,512]
    const float* __restrict__ rescale, // [8]
    float* __restrict__ att_part)      // [1024,1536]
{
    __shared__ __align__(16) float smem[7696];  // 30.8 KB union
    float* xs   = smem;               // stage: [64 tok][64 c]     [0,4096)
    float* ms   = smem + 4096;        // stage: [64 tok][24 i]     [4096,5632)
    float* part = smem;               // merge: [4][1540]          [0,6160)
    float* Sp_l = smem + 6160;        // reduced Sp [24][64]       [6160,7696)
    float* S_l  = smem;               // S rows [24][64]           [0,1536)
    float* wq_l = smem + 1536;        // Wq h-slice [64][68]       [1536,5888)

    const int tid = threadIdx.x;
    const int blk = blockIdx.x;
    const int b = blk >> 8, chunk = blk & 255;
    const int w = tid >> 6, lane = tid & 63;
    const int cq = lane & 15;         // c = cq*4
    const int ig = lane >> 4;         // i = ig*6 .. +5

    const long tok0 = (long)b * NN + chunk * 64;

    // ---- stage 64 tokens: fully coalesced float4 (v6-proven) ----
    {
        const float4* xg = (const float4*)(x + tok0 * 64);     // 1024 float4
        float4* xs4 = (float4*)xs;
        #pragma unroll
        for (int e = 0; e < 4; ++e) xs4[tid + e * 256] = xg[tid + e * 256];
        const float4* mg = (const float4*)(imap + tok0 * 24);  // 384 float4
        float4* ms4 = (float4*)ms;
        if (tid < 128) {
            ms4[tid]       = mg[tid];
            ms4[tid + 128] = mg[tid + 128];
            ms4[tid + 256] = mg[tid + 256];
        }
    }
    __syncthreads();

    // ---- compute partial acc from LDS: wave w owns tokens w*16..+15 ----
    float acc[6][4];
    #pragma unroll
    for (int r = 0; r < 6; ++r)
        #pragma unroll
        for (int q = 0; q < 4; ++q) acc[r][q] = 0.f;
    {
        const float* xp = xs + w * 16 * 64 + cq * 4;
        const float* mp = ms + w * 16 * 24 + ig * 6;
        #pragma unroll 4
        for (int t = 0; t < 16; ++t) {
            float4 xv = *(const float4*)(xp + t * 64);
            float2 m0 = *(const float2*)(mp + t * 24);
            float2 m1 = *(const float2*)(mp + t * 24 + 2);
            float2 m2 = *(const float2*)(mp + t * 24 + 4);
            float mm[6] = {m0.x, m0.y, m1.x, m1.y, m2.x, m2.y};
            #pragma unroll
            for (int r = 0; r < 6; ++r) {
                acc[r][0] += mm[r] * xv.x;
                acc[r][1] += mm[r] * xv.y;
                acc[r][2] += mm[r] * xv.z;
                acc[r][3] += mm[r] * xv.w;
            }
        }
    }
    __syncthreads();   // stage dead; part may overwrite

    float* pp = part + w * 1540;
    #pragma unroll
    for (int r = 0; r < 6; ++r) {
        float4 v = {acc[r][0], acc[r][1], acc[r][2], acc[r][3]};
        *(float4*)(pp + (ig * 6 + r) * 64 + cq * 4) = v;
    }
    __syncthreads();

    for (int e = tid; e < 1536; e += 256)
        Sp_l[e] = part[e] + part[1540 + e] + part[3080 + e] + part[4620 + e];
    __syncthreads();   // part dead; S_l may overwrite

    // ---- E: S[ch,c] = sum_i Wk[i,ch]*Sp[i,c] (Wk wave-uniform scalar) ----
    for (int e = tid; e < 1536; e += 256) {
        const int c = e & 63, ch = e >> 6;
        float s = 0.f;
        #pragma unroll
        for (int i = 0; i < 24; ++i) s += Wk[i * 24 + ch] * Sp_l[i * 64 + c];
        S_l[e] = s;
    }
    __syncthreads();

    // ---- F: per-h att_blk = S_l x Wq_h * QSCALE*rescale[h] ----
    const long outbase = (long)blk * 1536;
    for (int h = 0; h < 8; ++h) {
        {   // stage Wq[:, h*64..+63] -> wq_l [64][68] (pad, conflict-free)
            float4* wq4 = (float4*)(smem + 1536);
            const float4* Wq4 = (const float4*)Wq;   // row stride 128 f4
            for (int t = tid; t < 1024; t += 256) {
                const int c = t >> 4, r = t & 15;
                wq4[c * 17 + r] = Wq4[c * 128 + h * 16 + r];
            }
        }
        __syncthreads();
        if (tid < 192) {
            const int d = tid & 63, ch3 = tid >> 6;
            const float* sr = S_l + (h * 3 + ch3) * 64;
            float s = 0.f;
            #pragma unroll 8
            for (int c = 0; c < 64; ++c) s += sr[c] * wq_l[c * 68 + d];
            att_part[outbase + h * 192 + tid] = s * QSCALE * rescale[h];
        }
        __syncthreads();   // before next h overwrites wq_l
    }
}

// ---------------------------------------------------------------------------
// K2': row-parallel slab reduce + softmax + V-projection. grid 96 x 256:
// block (b, ch). Reduce att row ch over 256 slabs (coalesced 256B, same
// pattern as R12-proven slab_reduce), wave-0 softmax, M row = P.Wv_h slice
// (LDS-staged), store Ms[4][24][64]. Replaces slab_reduce + attn_fused.
// ---------------------------------------------------------------------------
__global__ __launch_bounds__(256) void row_attn(
    const float* __restrict__ att_part, // [1024,1536]
    const float* __restrict__ Wv,       // [64,512]
    float* __restrict__ Ms)             // [4,1536]
{
    __shared__ float red[256];
    __shared__ float pl[64];
    __shared__ __align__(16) float wv_l[64 * 68];

    const int tid = threadIdx.x, blk = blockIdx.x;
    const int b = blk / 24, ch = blk % 24, h = ch / 3;
    const int d = tid & 63, q = tid >> 6;

    // ---- reduce row ch over this wave's 64 slabs ----
    {
        const float* p = att_part + ((long)(b * 256 + q * 64)) * 1536 + ch * 64 + d;
        float s = 0.f;
        #pragma unroll 16
        for (int sb = 0; sb < 64; ++sb) s += p[(long)sb * 1536];
        red[tid] = s;
    }
    __syncthreads();

    // ---- wave 0: final merge + softmax; others stage Wv slice ----
    if (tid < 64) {
        float a = red[tid] + red[64 + tid] + red[128 + tid] + red[192 + tid];
        float mx = a;
        #pragma unroll
        for (int off = 32; off >= 1; off >>= 1)
            mx = fmaxf(mx, __shfl_xor(mx, off, 64));
        float e = expf(a - mx);
        float sum = e;
        #pragma unroll
        for (int off = 32; off >= 1; off >>= 1)
            sum += __shfl_xor(sum, off, 64);
        pl[tid] = e / sum;
    }
    {   // stage Wv[:, h*64..+63] -> wv_l [64][68]
        float4* wv4 = (float4*)wv_l;
        const float4* Wv4 = (const float4*)Wv;   // row stride 128 f4
        for (int t = tid; t < 1024; t += 256) {
            const int c = t >> 4, r = t & 15;
            wv4[c * 17 + r] = Wv4[c * 128 + h * 16 + r];
        }
    }
    __syncthreads();

    // ---- M[ch,c] = sum_d P[d] * Wv[c, h*64+d]: thread (c, d-quarter) ----
    {
        const int c = tid & 63;
        const float* wvr = wv_l + c * 68 + q * 16;
        const float* pr = pl + q * 16;
        float m = 0.f;
        #pragma unroll
        for (int j = 0; j < 16; ++j) m += pr[j] * wvr[j];
        red[tid] = m;
    }
    __syncthreads();
    if (tid < 64)
        Ms[b * 1536 + ch * 64 + tid] =
            red[tid] + red[64 + tid] + red[128 + tid] + red[192 + tid];
}

// ---------------------------------------------------------------------------
// K3': conv (R9-proven body incl. ptl) + pre-phase computing Pt = Ms x Wp
// into ptl (1536 outputs x 24 MAC from LDS -- trivial). Ml uses the kbuf
// region (dead pre-ph1); ptl survives in [7152,8784) exactly as R9.
// ---------------------------------------------------------------------------
__global__ __launch_bounds__(192, 2) void conv_fused(
    const float* __restrict__ imap, const float* __restrict__ Wk,
    const float* __restrict__ c1w,  const float* __restrict__ fea,
    const float* __restrict__ c2w,  const float* __restrict__ Ms,
    const float* __restrict__ Wp,   const float* __restrict__ bp,
    float* __restrict__ outp)
{
    __shared__ __align__(16) float smem[8784];
    float* Ml   = smem;               // pre: [0,1536)
    float* kbuf = smem;               // ph1/ph2: 144*28 = 4032
    float* feat = smem;               // ph3: 64 pix * 68 = 4352
    float* y1l  = smem + 4352;        // 100*28 = 2800
    float* ptl  = smem + 7152;        // 24*68 = 1632

    const int tid = threadIdx.x;
    const int blk = blockIdx.x;
    const int b = blk >> 8, ti = (blk >> 4) & 15, tj = blk & 15;
    const int i0 = ti * 8, j0 = tj * 8;
    const int o = tid % 24, jj = tid / 24;   // o: out-channel; jj: 0..7
    const int g = o >> 3;

    // ---- pre-phase: ptl[o][c] = bias-free Pt = sum_{k,h} M[(h3k),c]Wp ----
    {
        for (int e = tid; e < 1536; e += 192) Ml[e] = Ms[b * 1536 + e];
        __syncthreads();
        for (int e = tid; e < 1536; e += 192) {
            const int oo = e >> 6, c = e & 63;
            float s = 0.f;
            #pragma unroll
            for (int k = 0; k < 3; ++k)
                #pragma unroll
                for (int h = 0; h < 8; ++h)
                    s += Ml[(h * 3 + k) * 64 + c] * Wp[(k * 8 + h) * 24 + oo];
            ptl[oo * 68 + c] = s;
        }
        __syncthreads();   // Ml dead; kbuf may overwrite
    }

    // ---- phase 1: kproj on the 12x12 halo (threads 0..143) ----
    if (tid < 144) {
        const int pi = tid / 12, pj = tid % 12;
        const int gi = i0 + pi - 2, gj = j0 + pj - 2;
        float kv[24];
        #pragma unroll
        for (int j = 0; j < 24; ++j) kv[j] = 0.f;
        if (gi >= 0 && gi < HH && gj >= 0 && gj < WW) {
            const float4* m4 = (const float4*)(imap + (((long)b * HH + gi) * WW + gj) * 24);
            float m[24];
            #pragma unroll
            for (int i = 0; i < 6; ++i) {
                float4 v = m4[i];
                m[4*i+0]=v.x; m[4*i+1]=v.y; m[4*i+2]=v.z; m[4*i+3]=v.w;
            }
            for (int i = 0; i < 24; ++i) {
                float mi = m[i];
                #pragma unroll
                for (int j = 0; j < 24; ++j) kv[j] += mi * Wk[i * 24 + j];
            }
        }
        #pragma unroll
        for (int j = 0; j < 24; ++j) kbuf[tid * 28 + j] = kv[j];
    }
    __syncthreads();

    // ---- phase 2: y1 = gelu(conv1) on 10x10 -> y1l ----
    {
        float wr[8][9];   // wr[ic][di*3+dj], OIHW-linear
        {
            const float4* wp = (const float4*)(c1w + o * 72);
            #pragma unroll
            for (int t = 0; t < 18; ++t) ((float4*)wr)[t] = wp[t];
        }
        for (int task = tid; task < 240; task += 192) {
            const int r = task / 24;           // y1l row 0..9
            float wc[3][3][8];                 // [col slot][di][ic]
            #pragma unroll
            for (int slot = 0; slot < 2; ++slot)
                #pragma unroll
                for (int di = 0; di < 3; ++di) {
                    const float* p = kbuf + ((r + di) * 12 + slot) * 28 + g * 8;
                    *(float4*)&wc[slot][di][0] = *(const float4*)(p);
                    *(float4*)&wc[slot][di][4] = *(const float4*)(p + 4);
                }
            #pragma unroll
            for (int c = 0; c < 10; ++c) {
                const int s2 = (c + 2) % 3;
                #pragma unroll
                for (int di = 0; di < 3; ++di) {
                    const float* p = kbuf + ((r + di) * 12 + (c + 2)) * 28 + g * 8;
                    *(float4*)&wc[s2][di][0] = *(const float4*)(p);
                    *(float4*)&wc[s2][di][4] = *(const float4*)(p + 4);
                }
                float s = 0.f;
                #pragma unroll
                for (int dj = 0; dj < 3; ++dj) {
                    const int sl = (c + dj) % 3;
                    #pragma unroll
                    for (int di = 0; di < 3; ++di)
                        #pragma unroll
                        for (int ic = 0; ic < 8; ++ic)
                            s += wc[sl][di][ic] * wr[ic][di * 3 + dj];
                }
                const int gi = i0 + r - 1, gj = j0 + c - 1;
                float val = 0.f;
                if (gi >= 0 && gi < HH && gj >= 0 && gj < WW)
                    val = 0.5f * s * (1.f + erff(s * 0.70710678f));
                y1l[(r * 10 + c) * 28 + o] = val;
            }
        }
    }
    __syncthreads();   // kbuf dead; feat may now overwrite it

    // ---- phase 3a: stage fea tile into LDS (coalesced, stride 68) ----
    {
        const float4* feaT4 = (const float4*)(fea + (((long)(b * HH + i0)) * WW + j0) * 64);
        float4* feat4 = (float4*)feat;
        for (int e = tid; e < 1024; e += 192) {
            const int pix = e >> 4, cq = e & 15;      // pix = ii*8+jj
            feat4[pix * 17 + cq] =
                feaT4[((long)(pix >> 3) * WW + (pix & 7)) * 16 + cq];
        }
    }
    __syncthreads();

    // ---- phase 3b: proj (ptl + fea from LDS) + conv2(y1l) ----
    float wr[8][9];
    {
        const float4* wp = (const float4*)(c2w + o * 72);
        #pragma unroll
        for (int t = 0; t < 18; ++t) ((float4*)wr)[t] = wp[t];
    }

    float acc[8];
    {
        const float bo = bp[o];
        #pragma unroll
        for (int ii = 0; ii < 8; ++ii) acc[ii] = bo;
        const float4* pr4 = (const float4*)(ptl + o * 68);
        for (int cq = 0; cq < 16; ++cq) {
            float4 p = pr4[cq];
            #pragma unroll
            for (int ii = 0; ii < 8; ++ii) {
                float4 f = ((const float4*)(feat + (ii * 8 + jj) * 68))[cq];
                acc[ii] += f.x * p.x + f.y * p.y + f.z * p.z + f.w * p.w;
            }
        }
    }

    float win[3][3][8];   // [row slot][dj][ic]
    #define LROW(R, SLOT)                                                     \
    {                                                                         \
        const float* rp_ = y1l + ((R) * 10 + jj) * 28 + g * 8;                \
        *(float4*)&win[SLOT][0][0] = *(const float4*)(rp_);                   \
        *(float4*)&win[SLOT][0][4] = *(const float4*)(rp_ + 4);               \
        *(float4*)&win[SLOT][1][0] = *(const float4*)(rp_ + 28);              \
        *(float4*)&win[SLOT][1][4] = *(const float4*)(rp_ + 32);              \
        *(float4*)&win[SLOT][2][0] = *(const float4*)(rp_ + 56);              \
        *(float4*)&win[SLOT][2][4] = *(const float4*)(rp_ + 60);              \
    }

    LROW(0, 0)
    LROW(1, 1)
    #pragma unroll
    for (int ii = 0; ii < 8; ++ii) {
        LROW(ii + 2, (ii + 2) % 3)
        float s = 0.f;
        #pragma unroll
        for (int di = 0; di < 3; ++di) {
            const int slot = (ii + di) % 3;
            #pragma unroll
            for (int dj = 0; dj < 3; ++dj)
                #pragma unroll
                for (int ic = 0; ic < 8; ++ic)
                    s += win[slot][dj][ic] * wr[ic][di * 3 + dj];
        }
        outp[((long)((b * HH + i0 + ii) * WW + j0)) * 24 + tid] = acc[ii] + s;
    }
    #undef LROW
}

// ---------------------------------------------------------------------------
extern "C" void kernel_launch(void* const* d_in, const int* in_sizes, int n_in,
                              void* d_out, int out_size, void* d_ws, size_t ws_size,
                              hipStream_t stream) {
    const float* x_in    = (const float*)d_in[0];
    const float* fea     = (const float*)d_in[1];
    const float* imap    = (const float*)d_in[2];
    const float* Wq      = (const float*)d_in[3];
    const float* Wk      = (const float*)d_in[4];
    const float* Wv      = (const float*)d_in[5];
    const float* rescale = (const float*)d_in[6];
    const float* Wp      = (const float*)d_in[7];
    const float* bp      = (const float*)d_in[8];
    const float* c1w     = (const float*)d_in[9];
    const float* c2w     = (const float*)d_in[10];
    float* out = (float*)d_out;

    float* ws       = (float*)d_ws;
    float* att_part = ws;                    // 1024*1536 = 1,572,864 floats
    float* Ms       = ws + 1572864;          // 6,144 floats

    s_reduce_proj<<<1024, 256, 0, stream>>>(imap, x_in, Wk, Wq, rescale, att_part);
    row_attn<<<96, 256, 0, stream>>>(att_part, Wv, Ms);
    conv_fused<<<BB * 256, 192, 0, stream>>>(imap, Wk, c1w, fea, c2w, Ms, Wp, bp, out);
}

// Round 15
// 166.353 us; speedup vs baseline: 1.0004x; 1.0004x over previous
//
#include <hip/hip_runtime.h>
#include <math.h>

#define HEADS 8
#define DIM   64
#define DK    24
#define DHK   3
#define BB    4
#define HH    128
#define WW    128
#define NN    (HH*WW)
#define QSCALE 0.125f

// ---------------------------------------------------------------------------
// K1' (R14, verbatim): token-partial reduce + in-block projection to
// att-space (linear ops commute with the token sum). grid 1024 x 256.
// ---------------------------------------------------------------------------
__global__ __launch_bounds__(256) void s_reduce_proj(
    const float* __restrict__ imap,    // [B*N,24]
    const float* __restrict__ x,       // [B*N,64]
    const float* __restrict__ Wk,      // [24,24]
    const float* __restrict__ Wq,      // [64,512]
    const float* __restrict__ rescale, // [8]
    float* __restrict__ att_part)      // [1024,1536]
{
    __shared__ __align__(16) float smem[7696];  // 30.8 KB union
    float* xs   = smem;               // stage: [64 tok][64 c]     [0,4096)
    float* ms   = smem + 4096;        // stage: [64 tok][24 i]     [4096,5632)
    float* part = smem;               // merge: [4][1540]          [0,6160)
    float* Sp_l = smem + 6160;        // reduced Sp [24][64]       [6160,7696)
    float* S_l  = smem;               // S rows [24][64]           [0,1536)
    float* wq_l = smem + 1536;        // Wq h-slice [64][68]       [1536,5888)

    const int tid = threadIdx.x;
    const int blk = blockIdx.x;
    const int b = blk >> 8, chunk = blk & 255;
    const int w = tid >> 6, lane = tid & 63;
    const int cq = lane & 15;         // c = cq*4
    const int ig = lane >> 4;         // i = ig*6 .. +5

    const long tok0 = (long)b * NN + chunk * 64;

    // ---- stage 64 tokens: fully coalesced float4 ----
    {
        const float4* xg = (const float4*)(x + tok0 * 64);     // 1024 float4
        float4* xs4 = (float4*)xs;
        #pragma unroll
        for (int e = 0; e < 4; ++e) xs4[tid + e * 256] = xg[tid + e * 256];
        const float4* mg = (const float4*)(imap + tok0 * 24);  // 384 float4
        float4* ms4 = (float4*)ms;
        if (tid < 128) {
            ms4[tid]       = mg[tid];
            ms4[tid + 128] = mg[tid + 128];
            ms4[tid + 256] = mg[tid + 256];
        }
    }
    __syncthreads();

    // ---- compute partial acc from LDS: wave w owns tokens w*16..+15 ----
    float acc[6][4];
    #pragma unroll
    for (int r = 0; r < 6; ++r)
        #pragma unroll
        for (int q = 0; q < 4; ++q) acc[r][q] = 0.f;
    {
        const float* xp = xs + w * 16 * 64 + cq * 4;
        const float* mp = ms + w * 16 * 24 + ig * 6;
        #pragma unroll 4
        for (int t = 0; t < 16; ++t) {
            float4 xv = *(const float4*)(xp + t * 64);
            float2 m0 = *(const float2*)(mp + t * 24);
            float2 m1 = *(const float2*)(mp + t * 24 + 2);
            float2 m2 = *(const float2*)(mp + t * 24 + 4);
            float mm[6] = {m0.x, m0.y, m1.x, m1.y, m2.x, m2.y};
            #pragma unroll
            for (int r = 0; r < 6; ++r) {
                acc[r][0] += mm[r] * xv.x;
                acc[r][1] += mm[r] * xv.y;
                acc[r][2] += mm[r] * xv.z;
                acc[r][3] += mm[r] * xv.w;
            }
        }
    }
    __syncthreads();   // stage dead; part may overwrite

    float* pp = part + w * 1540;
    #pragma unroll
    for (int r = 0; r < 6; ++r) {
        float4 v = {acc[r][0], acc[r][1], acc[r][2], acc[r][3]};
        *(float4*)(pp + (ig * 6 + r) * 64 + cq * 4) = v;
    }
    __syncthreads();

    for (int e = tid; e < 1536; e += 256)
        Sp_l[e] = part[e] + part[1540 + e] + part[3080 + e] + part[4620 + e];
    __syncthreads();   // part dead; S_l may overwrite

    // ---- E: S[ch,c] = sum_i Wk[i,ch]*Sp[i,c] ----
    for (int e = tid; e < 1536; e += 256) {
        const int c = e & 63, ch = e >> 6;
        float s = 0.f;
        #pragma unroll
        for (int i = 0; i < 24; ++i) s += Wk[i * 24 + ch] * Sp_l[i * 64 + c];
        S_l[e] = s;
    }
    __syncthreads();

    // ---- F: per-h att_blk = S_l x Wq_h * QSCALE*rescale[h] ----
    const long outbase = (long)blk * 1536;
    for (int h = 0; h < 8; ++h) {
        {   // stage Wq[:, h*64..+63] -> wq_l [64][68]
            float4* wq4 = (float4*)(smem + 1536);
            const float4* Wq4 = (const float4*)Wq;   // row stride 128 f4
            for (int t = tid; t < 1024; t += 256) {
                const int c = t >> 4, r = t & 15;
                wq4[c * 17 + r] = Wq4[c * 128 + h * 16 + r];
            }
        }
        __syncthreads();
        if (tid < 192) {
            const int d = tid & 63, ch3 = tid >> 6;
            const float* sr = S_l + (h * 3 + ch3) * 64;
            float s = 0.f;
            #pragma unroll 8
            for (int c = 0; c < 64; ++c) s += sr[c] * wq_l[c * 68 + d];
            att_part[outbase + h * 192 + tid] = s * QSCALE * rescale[h];
        }
        __syncthreads();   // before next h overwrites wq_l
    }
}

// ---------------------------------------------------------------------------
// K2' (R14, verbatim): row-parallel slab reduce + softmax + V-projection.
// grid 96 x 256: block (b, ch).
// ---------------------------------------------------------------------------
__global__ __launch_bounds__(256) void row_attn(
    const float* __restrict__ att_part, // [1024,1536]
    const float* __restrict__ Wv,       // [64,512]
    float* __restrict__ Ms)             // [4,1536]
{
    __shared__ float red[256];
    __shared__ float pl[64];
    __shared__ __align__(16) float wv_l[64 * 68];

    const int tid = threadIdx.x, blk = blockIdx.x;
    const int b = blk / 24, ch = blk % 24, h = ch / 3;
    const int d = tid & 63, q = tid >> 6;

    {
        const float* p = att_part + ((long)(b * 256 + q * 64)) * 1536 + ch * 64 + d;
        float s = 0.f;
        #pragma unroll 16
        for (int sb = 0; sb < 64; ++sb) s += p[(long)sb * 1536];
        red[tid] = s;
    }
    __syncthreads();

    if (tid < 64) {
        float a = red[tid] + red[64 + tid] + red[128 + tid] + red[192 + tid];
        float mx = a;
        #pragma unroll
        for (int off = 32; off >= 1; off >>= 1)
            mx = fmaxf(mx, __shfl_xor(mx, off, 64));
        float e = expf(a - mx);
        float sum = e;
        #pragma unroll
        for (int off = 32; off >= 1; off >>= 1)
            sum += __shfl_xor(sum, off, 64);
        pl[tid] = e / sum;
    }
    {   // stage Wv[:, h*64..+63] -> wv_l [64][68]
        float4* wv4 = (float4*)wv_l;
        const float4* Wv4 = (const float4*)Wv;   // row stride 128 f4
        for (int t = tid; t < 1024; t += 256) {
            const int c = t >> 4, r = t & 15;
            wv4[c * 17 + r] = Wv4[c * 128 + h * 16 + r];
        }
    }
    __syncthreads();

    {
        const int c = tid & 63;
        const float* wvr = wv_l + c * 68 + q * 16;
        const float* pr = pl + q * 16;
        float m = 0.f;
        #pragma unroll
        for (int j = 0; j < 16; ++j) m += pr[j] * wvr[j];
        red[tid] = m;
    }
    __syncthreads();
    if (tid < 64)
        Ms[b * 1536 + ch * 64 + tid] =
            red[tid] + red[64 + tid] + red[128 + tid] + red[192 + tid];
}

// ---------------------------------------------------------------------------
// K3': conv (R14 body) with ONE change: ph2 task split 240 full-rows ->
// 480 half-rows (5 cols). Old: 48 threads ran 2 erff-heavy tasks (20 cols
// critical path) while 144 waited at the barrier. New: 96x3 + 96x2 halves
// -> 15-col critical path (-25% ph2 serial length). Decomposition identical
// to R2's proven 384-thr variant (relative slot indexing, c0 = half*5).
// wr still loads once (480 % 24 == 0 under stride 192).
// ---------------------------------------------------------------------------
__global__ __launch_bounds__(192, 2) void conv_fused(
    const float* __restrict__ imap, const float* __restrict__ Wk,
    const float* __restrict__ c1w,  const float* __restrict__ fea,
    const float* __restrict__ c2w,  const float* __restrict__ Ms,
    const float* __restrict__ Wp,   const float* __restrict__ bp,
    float* __restrict__ outp)
{
    __shared__ __align__(16) float smem[8784];
    float* Ml   = smem;               // pre: [0,1536)
    float* kbuf = smem;               // ph1/ph2: 144*28 = 4032
    float* feat = smem;               // ph3: 64 pix * 68 = 4352
    float* y1l  = smem + 4352;        // 100*28 = 2800
    float* ptl  = smem + 7152;        // 24*68 = 1632

    const int tid = threadIdx.x;
    const int blk = blockIdx.x;
    const int b = blk >> 8, ti = (blk >> 4) & 15, tj = blk & 15;
    const int i0 = ti * 8, j0 = tj * 8;
    const int o = tid % 24, jj = tid / 24;   // o: out-channel; jj: 0..7
    const int g = o >> 3;

    // ---- pre-phase: ptl[o][c] = sum_{k,h} Ms[(h3k),c] * Wp ----
    {
        for (int e = tid; e < 1536; e += 192) Ml[e] = Ms[b * 1536 + e];
        __syncthreads();
        for (int e = tid; e < 1536; e += 192) {
            const int oo = e >> 6, c = e & 63;
            float s = 0.f;
            #pragma unroll
            for (int k = 0; k < 3; ++k)
                #pragma unroll
                for (int h = 0; h < 8; ++h)
                    s += Ml[(h * 3 + k) * 64 + c] * Wp[(k * 8 + h) * 24 + oo];
            ptl[oo * 68 + c] = s;
        }
        __syncthreads();   // Ml dead; kbuf may overwrite
    }

    // ---- phase 1: kproj on the 12x12 halo (threads 0..143) ----
    if (tid < 144) {
        const int pi = tid / 12, pj = tid % 12;
        const int gi = i0 + pi - 2, gj = j0 + pj - 2;
        float kv[24];
        #pragma unroll
        for (int j = 0; j < 24; ++j) kv[j] = 0.f;
        if (gi >= 0 && gi < HH && gj >= 0 && gj < WW) {
            const float4* m4 = (const float4*)(imap + (((long)b * HH + gi) * WW + gj) * 24);
            float m[24];
            #pragma unroll
            for (int i = 0; i < 6; ++i) {
                float4 v = m4[i];
                m[4*i+0]=v.x; m[4*i+1]=v.y; m[4*i+2]=v.z; m[4*i+3]=v.w;
            }
            for (int i = 0; i < 24; ++i) {
                float mi = m[i];
                #pragma unroll
                for (int j = 0; j < 24; ++j) kv[j] += mi * Wk[i * 24 + j];
            }
        }
        #pragma unroll
        for (int j = 0; j < 24; ++j) kbuf[tid * 28 + j] = kv[j];
    }
    __syncthreads();

    // ---- phase 2: y1 = gelu(conv1), 480 half-row tasks (5 cols each) ----
    {
        float wr[8][9];   // wr[ic][di*3+dj], OIHW-linear
        {
            const float4* wp = (const float4*)(c1w + o * 72);
            #pragma unroll
            for (int t = 0; t < 18; ++t) ((float4*)wr)[t] = wp[t];
        }
        for (int task = tid; task < 480; task += 192) {
            const int r = task / 48;           // y1l row 0..9
            const int half = (task / 24) & 1;
            const int c0 = half * 5;           // output cols c0..c0+4
            float wc[3][3][8];                 // [slot][di][ic], slot rel c0
            #pragma unroll
            for (int slot = 0; slot < 2; ++slot)
                #pragma unroll
                for (int di = 0; di < 3; ++di) {
                    const float* p = kbuf + ((r + di) * 12 + c0 + slot) * 28 + g * 8;
                    *(float4*)&wc[slot][di][0] = *(const float4*)(p);
                    *(float4*)&wc[slot][di][4] = *(const float4*)(p + 4);
                }
            #pragma unroll
            for (int c5 = 0; c5 < 5; ++c5) {
                const int s2 = (c5 + 2) % 3;
                #pragma unroll
                for (int di = 0; di < 3; ++di) {
                    const float* p = kbuf + ((r + di) * 12 + c0 + c5 + 2) * 28 + g * 8;
                    *(float4*)&wc[s2][di][0] = *(const float4*)(p);
                    *(float4*)&wc[s2][di][4] = *(const float4*)(p + 4);
                }
                float s = 0.f;
                #pragma unroll
                for (int dj = 0; dj < 3; ++dj) {
                    const int sl = (c5 + dj) % 3;
                    #pragma unroll
                    for (int di = 0; di < 3; ++di)
                        #pragma unroll
                        for (int ic = 0; ic < 8; ++ic)
                            s += wc[sl][di][ic] * wr[ic][di * 3 + dj];
                }
                const int gi = i0 + r - 1, gj = j0 + c0 + c5 - 1;
                float val = 0.f;
                if (gi >= 0 && gi < HH && gj >= 0 && gj < WW)
                    val = 0.5f * s * (1.f + erff(s * 0.70710678f));
                y1l[(r * 10 + c0 + c5) * 28 + o] = val;
            }
        }
    }
    __syncthreads();   // kbuf dead; feat may now overwrite it

    // ---- phase 3a: stage fea tile into LDS (coalesced, stride 68) ----
    {
        const float4* feaT4 = (const float4*)(fea + (((long)(b * HH + i0)) * WW + j0) * 64);
        float4* feat4 = (float4*)feat;
        for (int e = tid; e < 1024; e += 192) {
            const int pix = e >> 4, cq = e & 15;      // pix = ii*8+jj
            feat4[pix * 17 + cq] =
                feaT4[((long)(pix >> 3) * WW + (pix & 7)) * 16 + cq];
        }
    }
    __syncthreads();

    // ---- phase 3b: proj (ptl + fea from LDS) + conv2(y1l) ----
    float wr[8][9];
    {
        const float4* wp = (const float4*)(c2w + o * 72);
        #pragma unroll
        for (int t = 0; t < 18; ++t) ((float4*)wr)[t] = wp[t];
    }

    float acc[8];
    {
        const float bo = bp[o];
        #pragma unroll
        for (int ii = 0; ii < 8; ++ii) acc[ii] = bo;
        const float4* pr4 = (const float4*)(ptl + o * 68);
        for (int cq = 0; cq < 16; ++cq) {
            float4 p = pr4[cq];
            #pragma unroll
            for (int ii = 0; ii < 8; ++ii) {
                float4 f = ((const float4*)(feat + (ii * 8 + jj) * 68))[cq];
                acc[ii] += f.x * p.x + f.y * p.y + f.z * p.z + f.w * p.w;
            }
        }
    }

    float win[3][3][8];   // [row slot][dj][ic]
    #define LROW(R, SLOT)                                                     \
    {                                                                         \
        const float* rp_ = y1l + ((R) * 10 + jj) * 28 + g * 8;                \
        *(float4*)&win[SLOT][0][0] = *(const float4*)(rp_);                   \
        *(float4*)&win[SLOT][0][4] = *(const float4*)(rp_ + 4);               \
        *(float4*)&win[SLOT][1][0] = *(const float4*)(rp_ + 28);              \
        *(float4*)&win[SLOT][1][4] = *(const float4*)(rp_ + 32);              \
        *(float4*)&win[SLOT][2][0] = *(const float4*)(rp_ + 56);              \
        *(float4*)&win[SLOT][2][4] = *(const float4*)(rp_ + 60);              \
    }

    LROW(0, 0)
    LROW(1, 1)
    #pragma unroll
    for (int ii = 0; ii < 8; ++ii) {
        LROW(ii + 2, (ii + 2) % 3)
        float s = 0.f;
        #pragma unroll
        for (int di = 0; di < 3; ++di) {
            const int slot = (ii + di) % 3;
            #pragma unroll
            for (int dj = 0; dj < 3; ++dj)
                #pragma unroll
                for (int ic = 0; ic < 8; ++ic)
                    s += win[slot][dj][ic] * wr[ic][di * 3 + dj];
        }
        outp[((long)((b * HH + i0 + ii) * WW + j0)) * 24 + tid] = acc[ii] + s;
    }
    #undef LROW
}

// ---------------------------------------------------------------------------
extern "C" void kernel_launch(void* const* d_in, const int* in_sizes, int n_in,
                              void* d_out, int out_size, void* d_ws, size_t ws_size,
                              hipStream_t stream) {
    const float* x_in    = (const float*)d_in[0];
    const float* fea     = (const float*)d_in[1];
    const float* imap    = (const float*)d_in[2];
    const float* Wq      = (const float*)d_in[3];
    const float* Wk      = (const float*)d_in[4];
    const float* Wv      = (const float*)d_in[5];
    const float* rescale = (const float*)d_in[6];
    const float* Wp      = (const float*)d_in[7];
    const float* bp      = (const float*)d_in[8];
    const float* c1w     = (const float*)d_in[9];
    const float* c2w     = (const float*)d_in[10];
    float* out = (float*)d_out;

    float* ws       = (float*)d_ws;
    float* att_part = ws;                    // 1024*1536 = 1,572,864 floats
    float* Ms       = ws + 1572864;          // 6,144 floats

    s_reduce_proj<<<1024, 256, 0, stream>>>(imap, x_in, Wk, Wq, rescale, att_part);
    row_attn<<<96, 256, 0, stream>>>(att_part, Wv, Ms);
    conv_fused<<<BB * 256, 192, 0, stream>>>(imap, Wk, c1w, fea, c2w, Ms, Wp, bp, out);
}

// Round 16
// 162.970 us; speedup vs baseline: 1.0211x; 1.0208x over previous
//
#include <hip/hip_runtime.h>
#include <math.h>

#define HEADS 8
#define DIM   64
#define DK    24
#define DHK   3
#define BB    4
#define HH    128
#define WW    128
#define NN    (HH*WW)
#define QSCALE 0.125f

// ---------------------------------------------------------------------------
// K1' (R14, verbatim): token-partial reduce + in-block projection to
// att-space (linear ops commute with the token sum). grid 1024 x 256.
// ---------------------------------------------------------------------------
__global__ __launch_bounds__(256) void s_reduce_proj(
    const float* __restrict__ imap,    // [B*N,24]
    const float* __restrict__ x,       // [B*N,64]
    const float* __restrict__ Wk,      // [24,24]
    const float* __restrict__ Wq,      // [64,512]
    const float* __restrict__ rescale, // [8]
    float* __restrict__ att_part)      // [1024,1536]
{
    __shared__ __align__(16) float smem[7696];  // 30.8 KB union
    float* xs   = smem;               // stage: [64 tok][64 c]     [0,4096)
    float* ms   = smem + 4096;        // stage: [64 tok][24 i]     [4096,5632)
    float* part = smem;               // merge: [4][1540]          [0,6160)
    float* Sp_l = smem + 6160;        // reduced Sp [24][64]       [6160,7696)
    float* S_l  = smem;               // S rows [24][64]           [0,1536)
    float* wq_l = smem + 1536;        // Wq h-slice [64][68]       [1536,5888)

    const int tid = threadIdx.x;
    const int blk = blockIdx.x;
    const int b = blk >> 8, chunk = blk & 255;
    const int w = tid >> 6, lane = tid & 63;
    const int cq = lane & 15;         // c = cq*4
    const int ig = lane >> 4;         // i = ig*6 .. +5

    const long tok0 = (long)b * NN + chunk * 64;

    // ---- stage 64 tokens: fully coalesced float4 ----
    {
        const float4* xg = (const float4*)(x + tok0 * 64);     // 1024 float4
        float4* xs4 = (float4*)xs;
        #pragma unroll
        for (int e = 0; e < 4; ++e) xs4[tid + e * 256] = xg[tid + e * 256];
        const float4* mg = (const float4*)(imap + tok0 * 24);  // 384 float4
        float4* ms4 = (float4*)ms;
        if (tid < 128) {
            ms4[tid]       = mg[tid];
            ms4[tid + 128] = mg[tid + 128];
            ms4[tid + 256] = mg[tid + 256];
        }
    }
    __syncthreads();

    // ---- compute partial acc from LDS: wave w owns tokens w*16..+15 ----
    float acc[6][4];
    #pragma unroll
    for (int r = 0; r < 6; ++r)
        #pragma unroll
        for (int q = 0; q < 4; ++q) acc[r][q] = 0.f;
    {
        const float* xp = xs + w * 16 * 64 + cq * 4;
        const float* mp = ms + w * 16 * 24 + ig * 6;
        #pragma unroll 4
        for (int t = 0; t < 16; ++t) {
            float4 xv = *(const float4*)(xp + t * 64);
            float2 m0 = *(const float2*)(mp + t * 24);
            float2 m1 = *(const float2*)(mp + t * 24 + 2);
            float2 m2 = *(const float2*)(mp + t * 24 + 4);
            float mm[6] = {m0.x, m0.y, m1.x, m1.y, m2.x, m2.y};
            #pragma unroll
            for (int r = 0; r < 6; ++r) {
                acc[r][0] += mm[r] * xv.x;
                acc[r][1] += mm[r] * xv.y;
                acc[r][2] += mm[r] * xv.z;
                acc[r][3] += mm[r] * xv.w;
            }
        }
    }
    __syncthreads();   // stage dead; part may overwrite

    float* pp = part + w * 1540;
    #pragma unroll
    for (int r = 0; r < 6; ++r) {
        float4 v = {acc[r][0], acc[r][1], acc[r][2], acc[r][3]};
        *(float4*)(pp + (ig * 6 + r) * 64 + cq * 4) = v;
    }
    __syncthreads();

    for (int e = tid; e < 1536; e += 256)
        Sp_l[e] = part[e] + part[1540 + e] + part[3080 + e] + part[4620 + e];
    __syncthreads();   // part dead; S_l may overwrite

    // ---- E: S[ch,c] = sum_i Wk[i,ch]*Sp[i,c] ----
    for (int e = tid; e < 1536; e += 256) {
        const int c = e & 63, ch = e >> 6;
        float s = 0.f;
        #pragma unroll
        for (int i = 0; i < 24; ++i) s += Wk[i * 24 + ch] * Sp_l[i * 64 + c];
        S_l[e] = s;
    }
    __syncthreads();

    // ---- F: per-h att_blk = S_l x Wq_h * QSCALE*rescale[h] ----
    const long outbase = (long)blk * 1536;
    for (int h = 0; h < 8; ++h) {
        {   // stage Wq[:, h*64..+63] -> wq_l [64][68]
            float4* wq4 = (float4*)(smem + 1536);
            const float4* Wq4 = (const float4*)Wq;   // row stride 128 f4
            for (int t = tid; t < 1024; t += 256) {
                const int c = t >> 4, r = t & 15;
                wq4[c * 17 + r] = Wq4[c * 128 + h * 16 + r];
            }
        }
        __syncthreads();
        if (tid < 192) {
            const int d = tid & 63, ch3 = tid >> 6;
            const float* sr = S_l + (h * 3 + ch3) * 64;
            float s = 0.f;
            #pragma unroll 8
            for (int c = 0; c < 64; ++c) s += sr[c] * wq_l[c * 68 + d];
            att_part[outbase + h * 192 + tid] = s * QSCALE * rescale[h];
        }
        __syncthreads();   // before next h overwrites wq_l
    }
}

// ---------------------------------------------------------------------------
// K2' (R14, verbatim): row-parallel slab reduce + softmax + V-projection.
// grid 96 x 256: block (b, ch).
// ---------------------------------------------------------------------------
__global__ __launch_bounds__(256) void row_attn(
    const float* __restrict__ att_part, // [1024,1536]
    const float* __restrict__ Wv,       // [64,512]
    float* __restrict__ Ms)             // [4,1536]
{
    __shared__ float red[256];
    __shared__ float pl[64];
    __shared__ __align__(16) float wv_l[64 * 68];

    const int tid = threadIdx.x, blk = blockIdx.x;
    const int b = blk / 24, ch = blk % 24, h = ch / 3;
    const int d = tid & 63, q = tid >> 6;

    {
        const float* p = att_part + ((long)(b * 256 + q * 64)) * 1536 + ch * 64 + d;
        float s = 0.f;
        #pragma unroll 16
        for (int sb = 0; sb < 64; ++sb) s += p[(long)sb * 1536];
        red[tid] = s;
    }
    __syncthreads();

    if (tid < 64) {
        float a = red[tid] + red[64 + tid] + red[128 + tid] + red[192 + tid];
        float mx = a;
        #pragma unroll
        for (int off = 32; off >= 1; off >>= 1)
            mx = fmaxf(mx, __shfl_xor(mx, off, 64));
        float e = expf(a - mx);
        float sum = e;
        #pragma unroll
        for (int off = 32; off >= 1; off >>= 1)
            sum += __shfl_xor(sum, off, 64);
        pl[tid] = e / sum;
    }
    {   // stage Wv[:, h*64..+63] -> wv_l [64][68]
        float4* wv4 = (float4*)wv_l;
        const float4* Wv4 = (const float4*)Wv;   // row stride 128 f4
        for (int t = tid; t < 1024; t += 256) {
            const int c = t >> 4, r = t & 15;
            wv4[c * 17 + r] = Wv4[c * 128 + h * 16 + r];
        }
    }
    __syncthreads();

    {
        const int c = tid & 63;
        const float* wvr = wv_l + c * 68 + q * 16;
        const float* pr = pl + q * 16;
        float m = 0.f;
        #pragma unroll
        for (int j = 0; j < 16; ++j) m += pr[j] * wvr[j];
        red[tid] = m;
    }
    __syncthreads();
    if (tid < 64)
        Ms[b * 1536 + ch * 64 + tid] =
            red[tid] + red[64 + tid] + red[128 + tid] + red[192 + tid];
}

// ---------------------------------------------------------------------------
// K2c (NEW, tiny): Pt[b,o,c] = sum_{k,h} Ms[b,(h*3+k),c] * Wp[(k*8+h),o].
// grid 4 x 256, ~2us incl. launch (R13->R14 showed dispatch cost ~nil).
// Removes R14's in-conv pre-phase, which strictly PREPENDED a serial
// segment (Ml load, 2 barriers, matmul) to every conv block's chain --
// prime suspect for conv 44->51us.
// ---------------------------------------------------------------------------
__global__ __launch_bounds__(256) void pt_proj(
    const float* __restrict__ Ms,   // [4,1536]
    const float* __restrict__ Wp,   // [24,24]
    float* __restrict__ Pt)         // [4,1536]
{
    __shared__ float Ml[1536];
    const int tid = threadIdx.x, b = blockIdx.x;
    for (int e = tid; e < 1536; e += 256) Ml[e] = Ms[b * 1536 + e];
    __syncthreads();
    for (int e = tid; e < 1536; e += 256) {
        const int o = e >> 6, c = e & 63;
        float s = 0.f;
        #pragma unroll
        for (int k = 0; k < 3; ++k)
            #pragma unroll
            for (int h = 0; h < 8; ++h)
                s += Ml[(h * 3 + k) * 64 + c] * Wp[(k * 8 + h) * 24 + o];
        Pt[b * 1536 + e] = s;
    }
}

// ---------------------------------------------------------------------------
// K3: conv -- R13-proven structure (Pt from L2, feat LDS-staged, no ptl,
// LDS 28.6KB -> 5 blocks/CU) + R15's half-row ph2 (keeps the 7x bank-
// conflict reduction: 1018560 -> 142336).
// ---------------------------------------------------------------------------
__global__ __launch_bounds__(192, 2) void conv_fused(
    const float* __restrict__ imap, const float* __restrict__ Wk,
    const float* __restrict__ c1w,  const float* __restrict__ fea,
    const float* __restrict__ c2w,  const float* __restrict__ Pt,
    const float* __restrict__ bp,   float* __restrict__ outp)
{
    __shared__ __align__(16) float smem[7152];
    float* kbuf = smem;               // ph1/ph2: 144*28 = 4032
    float* feat = smem;               // ph3: 64 pix * 68 = 4352 (reuses kbuf)
    float* y1l  = smem + 4352;        // 100*28 = 2800

    const int tid = threadIdx.x;
    const int blk = blockIdx.x;
    const int b = blk >> 8, ti = (blk >> 4) & 15, tj = blk & 15;
    const int i0 = ti * 8, j0 = tj * 8;
    const int o = tid % 24, jj = tid / 24;   // o: out-channel; jj: 0..7
    const int g = o >> 3;

    // ---- phase 1: kproj on the 12x12 halo (threads 0..143) ----
    if (tid < 144) {
        const int pi = tid / 12, pj = tid % 12;
        const int gi = i0 + pi - 2, gj = j0 + pj - 2;
        float kv[24];
        #pragma unroll
        for (int j = 0; j < 24; ++j) kv[j] = 0.f;
        if (gi >= 0 && gi < HH && gj >= 0 && gj < WW) {
            const float4* m4 = (const float4*)(imap + (((long)b * HH + gi) * WW + gj) * 24);
            float m[24];
            #pragma unroll
            for (int i = 0; i < 6; ++i) {
                float4 v = m4[i];
                m[4*i+0]=v.x; m[4*i+1]=v.y; m[4*i+2]=v.z; m[4*i+3]=v.w;
            }
            for (int i = 0; i < 24; ++i) {
                float mi = m[i];
                #pragma unroll
                for (int j = 0; j < 24; ++j) kv[j] += mi * Wk[i * 24 + j];
            }
        }
        #pragma unroll
        for (int j = 0; j < 24; ++j) kbuf[tid * 28 + j] = kv[j];
    }
    __syncthreads();

    // ---- phase 2: y1 = gelu(conv1), 480 half-row tasks (5 cols each) ----
    {
        float wr[8][9];   // wr[ic][di*3+dj], OIHW-linear
        {
            const float4* wp = (const float4*)(c1w + o * 72);
            #pragma unroll
            for (int t = 0; t < 18; ++t) ((float4*)wr)[t] = wp[t];
        }
        for (int task = tid; task < 480; task += 192) {
            const int r = task / 48;           // y1l row 0..9
            const int half = (task / 24) & 1;
            const int c0 = half * 5;           // output cols c0..c0+4
            float wc[3][3][8];                 // [slot][di][ic], slot rel c0
            #pragma unroll
            for (int slot = 0; slot < 2; ++slot)
                #pragma unroll
                for (int di = 0; di < 3; ++di) {
                    const float* p = kbuf + ((r + di) * 12 + c0 + slot) * 28 + g * 8;
                    *(float4*)&wc[slot][di][0] = *(const float4*)(p);
                    *(float4*)&wc[slot][di][4] = *(const float4*)(p + 4);
                }
            #pragma unroll
            for (int c5 = 0; c5 < 5; ++c5) {
                const int s2 = (c5 + 2) % 3;
                #pragma unroll
                for (int di = 0; di < 3; ++di) {
                    const float* p = kbuf + ((r + di) * 12 + c0 + c5 + 2) * 28 + g * 8;
                    *(float4*)&wc[s2][di][0] = *(const float4*)(p);
                    *(float4*)&wc[s2][di][4] = *(const float4*)(p + 4);
                }
                float s = 0.f;
                #pragma unroll
                for (int dj = 0; dj < 3; ++dj) {
                    const int sl = (c5 + dj) % 3;
                    #pragma unroll
                    for (int di = 0; di < 3; ++di)
                        #pragma unroll
                        for (int ic = 0; ic < 8; ++ic)
                            s += wc[sl][di][ic] * wr[ic][di * 3 + dj];
                }
                const int gi = i0 + r - 1, gj = j0 + c0 + c5 - 1;
                float val = 0.f;
                if (gi >= 0 && gi < HH && gj >= 0 && gj < WW)
                    val = 0.5f * s * (1.f + erff(s * 0.70710678f));
                y1l[(r * 10 + c0 + c5) * 28 + o] = val;
            }
        }
    }
    __syncthreads();   // kbuf dead; feat may now overwrite it

    // ---- phase 3a: stage fea tile into LDS (coalesced, stride 68) ----
    {
        const float4* feaT4 = (const float4*)(fea + (((long)(b * HH + i0)) * WW + j0) * 64);
        float4* feat4 = (float4*)feat;
        for (int e = tid; e < 1024; e += 192) {
            const int pix = e >> 4, cq = e & 15;      // pix = ii*8+jj
            feat4[pix * 17 + cq] =
                feaT4[((long)(pix >> 3) * WW + (pix & 7)) * 16 + cq];
        }
    }
    __syncthreads();

    // ---- phase 3b: proj (Pt from L2, fea from LDS) + conv2(y1l) ----
    float wr[8][9];
    {
        const float4* wp = (const float4*)(c2w + o * 72);
        #pragma unroll
        for (int t = 0; t < 18; ++t) ((float4*)wr)[t] = wp[t];
    }

    float acc[8];
    {
        const float bo = bp[o];
        #pragma unroll
        for (int ii = 0; ii < 8; ++ii) acc[ii] = bo;
        const float4* pr4 = (const float4*)(Pt + b * 1536 + o * 64);
        for (int cq = 0; cq < 16; ++cq) {
            float4 p = pr4[cq];
            #pragma unroll
            for (int ii = 0; ii < 8; ++ii) {
                float4 f = ((const float4*)(feat + (ii * 8 + jj) * 68))[cq];
                acc[ii] += f.x * p.x + f.y * p.y + f.z * p.z + f.w * p.w;
            }
        }
    }

    float win[3][3][8];   // [row slot][dj][ic]
    #define LROW(R, SLOT)                                                     \
    {                                                                         \
        const float* rp_ = y1l + ((R) * 10 + jj) * 28 + g * 8;                \
        *(float4*)&win[SLOT][0][0] = *(const float4*)(rp_);                   \
        *(float4*)&win[SLOT][0][4] = *(const float4*)(rp_ + 4);               \
        *(float4*)&win[SLOT][1][0] = *(const float4*)(rp_ + 28);              \
        *(float4*)&win[SLOT][1][4] = *(const float4*)(rp_ + 32);              \
        *(float4*)&win[SLOT][2][0] = *(const float4*)(rp_ + 56);              \
        *(float4*)&win[SLOT][2][4] = *(const float4*)(rp_ + 60);              \
    }

    LROW(0, 0)
    LROW(1, 1)
    #pragma unroll
    for (int ii = 0; ii < 8; ++ii) {
        LROW(ii + 2, (ii + 2) % 3)
        float s = 0.f;
        #pragma unroll
        for (int di = 0; di < 3; ++di) {
            const int slot = (ii + di) % 3;
            #pragma unroll
            for (int dj = 0; dj < 3; ++dj)
                #pragma unroll
                for (int ic = 0; ic < 8; ++ic)
                    s += win[slot][dj][ic] * wr[ic][di * 3 + dj];
        }
        outp[((long)((b * HH + i0 + ii) * WW + j0)) * 24 + tid] = acc[ii] + s;
    }
    #undef LROW
}

// ---------------------------------------------------------------------------
extern "C" void kernel_launch(void* const* d_in, const int* in_sizes, int n_in,
                              void* d_out, int out_size, void* d_ws, size_t ws_size,
                              hipStream_t stream) {
    const float* x_in    = (const float*)d_in[0];
    const float* fea     = (const float*)d_in[1];
    const float* imap    = (const float*)d_in[2];
    const float* Wq      = (const float*)d_in[3];
    const float* Wk      = (const float*)d_in[4];
    const float* Wv      = (const float*)d_in[5];
    const float* rescale = (const float*)d_in[6];
    const float* Wp      = (const float*)d_in[7];
    const float* bp      = (const float*)d_in[8];
    const float* c1w     = (const float*)d_in[9];
    const float* c2w     = (const float*)d_in[10];
    float* out = (float*)d_out;

    float* ws       = (float*)d_ws;
    float* att_part = ws;                    // 1024*1536 = 1,572,864 floats
    float* Ms       = ws + 1572864;          // 6,144 floats
    float* Pt       = ws + 1579008;          // 6,144 floats

    s_reduce_proj<<<1024, 256, 0, stream>>>(imap, x_in, Wk, Wq, rescale, att_part);
    row_attn<<<96, 256, 0, stream>>>(att_part, Wv, Ms);
    pt_proj<<<4, 256, 0, stream>>>(Ms, Wp, Pt);
    conv_fused<<<BB * 256, 192, 0, stream>>>(imap, Wk, c1w, fea, c2w, Pt, bp, out);
}